// Round 4
// baseline (5975.893 us; speedup 1.0000x reference)
//
#include <hip/hip_runtime.h>
#include <hip/hip_bf16.h>

// LSTM DynamicRNN: B=128, T=512, D=256, H=512.
// Round 7 "self-validating records": the flag/ack sync machinery is deleted.
// Producers publish h as 16B records [8B data | 8B data^TAG(t)] with ONE
// global_store_dwordx4 sc0 sc1 (no ack wait, no flag store); consumers spin
// directly on the records (XOR check == arrival detection). Two parity
// planes + step induction make overwrites race-free; torn/stale reads fail
// validation and retry. 128 blocks x 512 threads (2 waves/SIMD, proven best
// shape). Wave-private everything: gate-interleaved MFMA columns (all 4
// gates in-wave), wave-private LDS transpose/assemble, wave-private x
// staging in LDS (keeps peak VGPRs ~210 < 256 cap). h-record loads are
// quarter-pipelined with counted vmcnt(8). Zero __syncthreads, zero atomics.

#define B_   128
#define T_   512
#define D_   256
#define H_   512
#define G4_  2048   // 4*H
#define NBLK 128
#define XROW 264    // staged x row stride in shorts (256 + 8 pad)
#define TAGK 0x9E3779B97F4A7C15ull
#define PLANE_BYTES (64 * 2 * 128 * 16)   // [ct64][nt2][row128] x 16B

typedef __attribute__((ext_vector_type(8))) short short8;
typedef __attribute__((ext_vector_type(4))) float float4v;
typedef __attribute__((ext_vector_type(4))) int   int4v;

__device__ inline unsigned short f2bf_bits(float f) {
    union { float f; unsigned u; } v; v.f = f;
    unsigned r = (v.u + 0x7FFFu + ((v.u >> 16) & 1u)) >> 16;
    return (unsigned short)r;
}

__device__ inline float sigmoid_fast(float x) {
    return 1.f / (1.f + __expf(-x));
}

__device__ inline float tanh_fast(float x) {
    float a = fabsf(x);
    float e = __expf(-2.f * a);
    float r = (1.f - e) / (1.f + e);
    return copysignf(r, x);
}

__device__ inline short8 pack_bf8(float4v a, float4v b) {
    short8 s;
    s[0] = (short)f2bf_bits(a[0]); s[1] = (short)f2bf_bits(a[1]);
    s[2] = (short)f2bf_bits(a[2]); s[3] = (short)f2bf_bits(a[3]);
    s[4] = (short)f2bf_bits(b[0]); s[5] = (short)f2bf_bits(b[1]);
    s[6] = (short)f2bf_bits(b[2]); s[7] = (short)f2bf_bits(b[3]);
    return s;
}

union ABu { short8 s8; unsigned long long u64[2]; };

// ---- h-record load / spin / consume macros (constant-folded args) ----
#define LOADQ(qb, q)                                                         \
    {                                                                        \
        _Pragma("unroll")                                                    \
        for (int j_ = 0; j_ < 4; ++j_) {                                     \
            const char* p0_ = cbase + (size_t)((q) * 4 + j_) * 16384;        \
            asm volatile("global_load_dwordx4 %0, %1, off sc0 sc1"           \
                         : "=v"(rec[qb][2 * j_]) : "v"(p0_));                \
            asm volatile("global_load_dwordx4 %0, %1, off sc0 sc1"           \
                         : "=v"(rec[qb][2 * j_ + 1]) : "v"(p0_ + 2048));     \
        }                                                                    \
    }

#define VALIDQ(qb, okv)                                                      \
    {                                                                        \
        okv = 1;                                                             \
        _Pragma("unroll")                                                    \
        for (int j_ = 0; j_ < 8; ++j_) {                                     \
            okv &= (int)((((unsigned)rec[qb][j_][0] ^                        \
                           (unsigned)rec[qb][j_][2]) == tagLo) &             \
                         (((unsigned)rec[qb][j_][1] ^                        \
                           (unsigned)rec[qb][j_][3]) == tagHi));             \
        }                                                                    \
    }

#define SPINQ(qb, q, LAST)                                                   \
    {                                                                        \
        if (LAST) asm volatile("s_waitcnt vmcnt(0)" ::: "memory");           \
        else      asm volatile("s_waitcnt vmcnt(8)" ::: "memory");           \
        __builtin_amdgcn_sched_barrier(0);                                   \
        int ok_;                                                             \
        VALIDQ(qb, ok_)                                                      \
        while (!__all(ok_)) {                                                \
            LOADQ(qb, q)                                                     \
            asm volatile("s_waitcnt vmcnt(0)" ::: "memory");                 \
            __builtin_amdgcn_sched_barrier(0);                               \
            VALIDQ(qb, ok_)                                                  \
        }                                                                    \
    }

#define MFMAQ(qb, q)                                                         \
    {                                                                        \
        _Pragma("unroll")                                                    \
        for (int j_ = 0; j_ < 4; ++j_) {                                     \
            ABu a_;                                                          \
            a_.u64[0] = ((unsigned long long)(unsigned)rec[qb][2*j_][0]) |   \
                        (((unsigned long long)(unsigned)rec[qb][2*j_][1]) << 32); \
            a_.u64[1] = ((unsigned long long)(unsigned)rec[qb][2*j_+1][0]) | \
                        (((unsigned long long)(unsigned)rec[qb][2*j_+1][1]) << 32); \
            acc = __builtin_amdgcn_mfma_f32_16x16x32_bf16(                   \
                      a_.s8, wfrag[8 + (q) * 4 + j_], acc, 0, 0, 0);         \
        }                                                                    \
    }

__global__ __launch_bounds__(512, 2) void lstm_rec(
    const float* __restrict__ x, const float* __restrict__ Wx,
    const float* __restrict__ Wh, const float* __restrict__ bias,
    float* __restrict__ out, char* __restrict__ hrec)
{
    const int tid  = threadIdx.x;
    const int lane = tid & 63;
    const int wave = tid >> 6;          // 0..7
    const int ms   = wave & 3;          // batch strip (16 rows)
    const int nt   = wave >> 2;         // unit half (4 units)
    const int ct   = blockIdx.x & 63;   // hidden-unit tile: units ct*8..+7
    const int bt   = blockIdx.x >> 6;   // batch tile: rows bt*64..+63
    const int jh0  = ct * 8;
    const int l15  = lane & 15;
    const int l4   = lane >> 4;

    __shared__ __align__(16) unsigned short xw[8][16 * XROW]; // wave-private x
    __shared__ __align__(16) float zls[8][16 * 20];           // transpose
    __shared__ __align__(16) unsigned short als[8][64];       // h assemble

    // consumer A-frag rows (own ms strip)
    const int gb_a = bt * 64 + ms * 16 + l15;

    // gate-phase mapping: one (row,unit) per lane
    const int row_t  = lane >> 2;       // 0..15
    const int uu_t   = lane & 3;        // 0..3
    const int unit_t = jh0 + nt * 4 + uu_t;
    const int gb_t   = bt * 64 + ms * 16 + row_t;

    // ---- register-resident weight B-frags, gate-interleaved columns ----
    const int wcol = (l15 >> 2) * 512 + jh0 + nt * 4 + (l15 & 3);
    short8 wfrag[24];                   // ks 0..7 = Wx, 8..23 = Wh
#pragma unroll
    for (int ks = 0; ks < 24; ++ks) {
        short8 w;
#pragma unroll
        for (int j = 0; j < 8; ++j) {
            int k = ks * 32 + l4 * 8 + j;
            float v = (k < D_) ? Wx[(size_t)k * G4_ + wcol]
                               : Wh[(size_t)(k - D_) * G4_ + wcol];
            w[j] = (short)f2bf_bits(v);
        }
        wfrag[ks] = w;
    }

    const float bq0 = bias[0 * 512 + unit_t];
    const float bq1 = bias[1 * 512 + unit_t];
    const float bq2 = bias[2 * 512 + unit_t];
    const float bq3 = bias[3 * 512 + unit_t];

    // x staging: lane handles row lane>>2, 64 cols at (lane&3)*64
    const int xrow_l = lane >> 2;
    const int xcb    = lane & 3;
    const float* const xsrc =
        x + (size_t)(bt * 64 + ms * 16 + xrow_l) * (T_ * D_) + xcb * 64;
    unsigned short* const xwp = &xw[wave][xrow_l * XROW + xcb * 64];

    // record pointers
    // producer (lane<16): row = bt*64+ms*16+lane
    char* const pst = hrec +
        ((size_t)(ct * 2 + nt) * 128 + (bt * 64 + ms * 16 + lane)) * 16;
    // consumer base: + (ks*4+l4)*16384 (in LOADQ) + nt'*2048 + plane*PLANE_BYTES
    char* const cba = hrec + (size_t)l4 * 4096 + (size_t)gb_a * 16;

    float* const op = out + (size_t)gb_t * (T_ * H_) + unit_t;

    // ---- prologue: stage x_0, acc(0) = x-part, stage x_1 ----
    float4v xq[16];
    {
#pragma unroll
        for (int q2 = 0; q2 < 16; ++q2)
            asm volatile("global_load_dwordx4 %0, %1, off"
                         : "=v"(xq[q2]) : "v"(xsrc + q2 * 4));
        asm volatile("s_waitcnt vmcnt(0)" ::: "memory");
        __builtin_amdgcn_sched_barrier(0);
#pragma unroll
        for (int k = 0; k < 8; ++k)
            *(short8*)(xwp + k * 8) = pack_bf8(xq[2 * k], xq[2 * k + 1]);
    }
    float4v acc = {0.f, 0.f, 0.f, 0.f};
#pragma unroll
    for (int ks = 0; ks < 8; ++ks) {
        short8 a = *(const short8*)(&xw[wave][l15 * XROW + ks * 32 + l4 * 8]);
        acc = __builtin_amdgcn_mfma_f32_16x16x32_bf16(a, wfrag[ks], acc, 0, 0, 0);
    }
    {
        const float* xp = xsrc + D_;    // x_1
#pragma unroll
        for (int q2 = 0; q2 < 16; ++q2)
            asm volatile("global_load_dwordx4 %0, %1, off"
                         : "=v"(xq[q2]) : "v"(xp + q2 * 4));
        asm volatile("s_waitcnt vmcnt(0)" ::: "memory");
        __builtin_amdgcn_sched_barrier(0);
#pragma unroll
        for (int k = 0; k < 8; ++k)
            *(short8*)(xwp + k * 8) = pack_bf8(xq[2 * k], xq[2 * k + 1]);
    }

    float c_reg = 0.f, h_prev = 0.f;

    for (int t = 0; t < T_; ++t) {
        const unsigned long long tag_exp = TAGK * (unsigned long long)t;
        const unsigned tagLo = (unsigned)tag_exp;
        const unsigned tagHi = (unsigned)(tag_exp >> 32);
        const unsigned long long tag_pub = tag_exp + TAGK;

        // ---- (1/2) h phase: quarter-pipelined spin-validated loads ----
        if (t) {
            const char* cbase = cba + (size_t)(t & 1) * PLANE_BYTES;
            int4v rec[2][8];
            LOADQ(0, 0)
            LOADQ(1, 1)
            SPINQ(0, 0, false)
            __builtin_amdgcn_s_setprio(1);
            MFMAQ(0, 0)
            __builtin_amdgcn_s_setprio(0);
            LOADQ(0, 2)
            SPINQ(1, 1, false)
            __builtin_amdgcn_s_setprio(1);
            MFMAQ(1, 1)
            __builtin_amdgcn_s_setprio(0);
            LOADQ(1, 3)
            SPINQ(0, 2, false)
            __builtin_amdgcn_s_setprio(1);
            MFMAQ(0, 2)
            __builtin_amdgcn_s_setprio(0);
            SPINQ(1, 3, true)
            __builtin_amdgcn_s_setprio(1);
            MFMAQ(1, 3)
            __builtin_amdgcn_s_setprio(0);
        }

        // ---- (2b) issue x_{t+2} loads (RT hides under gates/publish) ----
        if (t + 2 < T_) {
            const float* xp = xsrc + (size_t)(t + 2) * D_;
#pragma unroll
            for (int q2 = 0; q2 < 16; ++q2)
                asm volatile("global_load_dwordx4 %0, %1, off"
                             : "=v"(xq[q2]) : "v"(xp + q2 * 4));
        }

        // ---- (3) wave-private transpose + gates ----
#pragma unroll
        for (int r = 0; r < 4; ++r)
            zls[wave][(l4 * 4 + r) * 20 + l15] = acc[r];
        asm volatile("s_waitcnt lgkmcnt(0)" ::: "memory");
        __builtin_amdgcn_sched_barrier(0);

        float zg0 = zls[wave][row_t * 20 + 0 + uu_t];
        float zg1 = zls[wave][row_t * 20 + 4 + uu_t];
        float zg2 = zls[wave][row_t * 20 + 8 + uu_t];
        float zg3 = zls[wave][row_t * 20 + 12 + uu_t];
        float ig = sigmoid_fast(zg0 + bq0);
        float fg = sigmoid_fast(zg1 + bq1);
        float gg = tanh_fast(zg2 + bq2);
        float og = sigmoid_fast(zg3 + bq3);
        c_reg = fg * c_reg + ig * gg;
        float hnew = og * tanh_fast(c_reg);

        // out store (plain; ack absorbed by loop-end drain)
        {
            const float* opt = op + (size_t)t * H_;
            asm volatile("global_store_dword %0, %1, off"
                         :: "v"(opt), "v"(hnew) : "memory");
        }

        // ---- (4) assemble + publish record (ONE 16B store, no ack) ----
        if (t + 1 < T_) {
            als[wave][lane] = f2bf_bits(hnew);
            asm volatile("s_waitcnt lgkmcnt(0)" ::: "memory");
            __builtin_amdgcn_sched_barrier(0);
            if (lane < 16) {
                unsigned long long d =
                    *(const unsigned long long*)(&als[wave][lane * 4]);
                unsigned long long sh = d ^ tag_pub;
                int4v st;
                st[0] = (int)(unsigned)d;         st[1] = (int)(unsigned)(d >> 32);
                st[2] = (int)(unsigned)sh;        st[3] = (int)(unsigned)(sh >> 32);
                char* p = pst + (size_t)((t + 1) & 1) * PLANE_BYTES;
                asm volatile("global_store_dwordx4 %0, %1, off sc0 sc1"
                             :: "v"(p), "v"(st) : "memory");
            }
        }

        // ---- (6) x-part MFMAs for t+1 (from LDS staged last iter) ----
        float4v nacc = {0.f, 0.f, 0.f, 0.f};
        if (t + 1 < T_) {
#pragma unroll
            for (int ks = 0; ks < 8; ++ks) {
                short8 a = *(const short8*)(
                    &xw[wave][l15 * XROW + ks * 32 + l4 * 8]);
                nacc = __builtin_amdgcn_mfma_f32_16x16x32_bf16(
                           a, wfrag[ks], nacc, 0, 0, 0);
            }
        }

        // ---- (7b) drain (x_{t+2} + record/out stores), stage x_{t+2} ----
        asm volatile("s_waitcnt vmcnt(0)" ::: "memory");
        __builtin_amdgcn_sched_barrier(0);
        if (t + 2 < T_) {
#pragma unroll
            for (int k = 0; k < 8; ++k)
                *(short8*)(xwp + k * 8) = pack_bf8(xq[2 * k], xq[2 * k + 1]);
        }

        acc = nacc;
        h_prev = hnew;
    }

    // ---- epilogue: final states ----
    const size_t BTH = (size_t)B_ * T_ * H_;
    out[BTH + (size_t)gb_t * H_ + unit_t] = h_prev;
    out[BTH + (size_t)B_ * H_ + (size_t)gb_t * H_ + unit_t] = c_reg;
}

extern "C" void kernel_launch(void* const* d_in, const int* in_sizes, int n_in,
                              void* d_out, int out_size, void* d_ws, size_t ws_size,
                              hipStream_t stream) {
    const float* x    = (const float*)d_in[0];
    const float* Wx   = (const float*)d_in[1];
    const float* Wh   = (const float*)d_in[2];
    const float* bias = (const float*)d_in[3];
    float* out = (float*)d_out;

    char* hrec = (char*)d_ws;   // 2 planes x [64][2][128] x 16B = 512 KiB

    hipMemsetAsync(d_ws, 0, (size_t)2 * PLANE_BYTES, stream);

    lstm_rec<<<dim3(NBLK), dim3(512), 0, stream>>>(
        x, Wx, Wh, bias, out, hrec);
}

// Round 5
// 4928.463 us; speedup vs baseline: 1.2125x; 1.2125x over previous
//
#include <hip/hip_runtime.h>
#include <hip/hip_bf16.h>

// LSTM DynamicRNN: B=128, T=512, D=256, H=512.
// Round 8 = Round-1 structure (best measured: 2250 us) with ONE change:
// consumer h loads go through the per-XCD L2 instead of L3-direct.
//   - producers keep write-through sc0 sc1 h-stores + vmcnt ack + flag
//     (data provably in L3 before the flag is visible).
//   - consumers: agent-scope ACQUIRE fence (compiler emits buffer_inv:
//     drops stale L2 lines) placed BEFORE the flag poll, then NORMAL
//     cacheable global_load_dwordx4 for h. First toucher per line per XCD
//     refills from L3; everyone else (incl. the nt-redundant twin wave)
//     hits L2/L1 -> h-distribution drops from ~16 MB/step of L3 traffic
//     to ~1-2 MB/step of L3 refills + L2-speed reads, and chain latency
//     drops ~700cy -> ~250cy.
//   - Safety: step skew <= 1 + parity-plane alternation => any plane-(t&1)
//     line cached after our inv was deposited by a same-step wave after
//     its own detect, i.e. final data. Fence at t=0 covers memset
//     visibility. Fence's implicit vmcnt drain overlaps producer skew.

#define B_   128
#define T_   512
#define D_   256
#define H_   512
#define G4_  2048   // 4*H
#define NBLK 128
#define KH   16     // h-part k-steps (K=512)
#define KX   8      // x-part k-steps (K=256)
#define XROW 264    // 256 + 8 pad (shorts) per staged x row

typedef __attribute__((ext_vector_type(8))) short short8;
typedef __attribute__((ext_vector_type(4))) short short4v;
typedef __attribute__((ext_vector_type(4))) float float4v;
typedef __attribute__((ext_vector_type(4))) int   int4v;

__device__ inline unsigned short f2bf_bits(float f) {
    union { float f; unsigned u; } v; v.f = f;
    unsigned r = (v.u + 0x7FFFu + ((v.u >> 16) & 1u)) >> 16;
    return (unsigned short)r;
}

__device__ inline float sigmoid_fast(float x) {
    return 1.f / (1.f + __expf(-x));
}

__device__ inline float tanh_fast(float x) {
    float a = fabsf(x);
    float e = __expf(-2.f * a);
    float r = (1.f - e) / (1.f + e);
    return copysignf(r, x);
}

__device__ inline short4v pack_bf4(float4v v) {
    short4v o;
    o[0] = (short)f2bf_bits(v[0]);
    o[1] = (short)f2bf_bits(v[1]);
    o[2] = (short)f2bf_bits(v[2]);
    o[3] = (short)f2bf_bits(v[3]);
    return o;
}

union HAu { int4v i4; short8 s8; };

__global__ __launch_bounds__(512, 2) void lstm_persistent(
    const float* __restrict__ x, const float* __restrict__ Wx,
    const float* __restrict__ Wh, const float* __restrict__ bias,
    float* __restrict__ out, unsigned short* __restrict__ hbuf,
    unsigned int* __restrict__ flags)
{
    const int tid  = threadIdx.x;
    const int lane = tid & 63;
    const int wave = tid >> 6;      // 8 waves
    const int ms   = wave & 3;      // M-strip (16 rows) within 64-batch tile
    const int nt   = wave >> 2;     // N-tile (16 cols) within 32 cols
    const int ct   = blockIdx.x & 63;   // column tile: hidden units ct*8..+7
    const int bt   = blockIdx.x >> 6;   // batch tile: batches bt*64..+63
    const int jh0  = ct * 8;

    __shared__ float zls[64 * 33];          // z tile, padded
    __shared__ float cls[64 * 8];           // c state
    __shared__ float bls[32];               // bias slice
    __shared__ unsigned short xls[2][64 * XROW];  // double-buffered x_t (bf16)

    for (int i = tid; i < 64 * 8; i += 512) cls[i] = 0.f;
    if (tid < 32) bls[tid] = bias[(tid >> 3) * 512 + jh0 + (tid & 7)];

    // ---- register-resident weight B-frags: ks 0..7 = Wx, ks 8..23 = Wh ----
    const int l15 = lane & 15;
    const int l4  = lane >> 4;
    const int ncol = nt * 16 + l15;
    const int col  = (ncol >> 3) * 512 + jh0 + (ncol & 7);
    short8 wfrag[KX + KH];
#pragma unroll
    for (int ks = 0; ks < KX + KH; ++ks) {
        short8 w;
#pragma unroll
        for (int j = 0; j < 8; ++j) {
            int k = ks * 32 + l4 * 8 + j;
            float v = (k < D_) ? Wx[(size_t)k * G4_ + col]
                               : Wh[(size_t)(k - D_) * G4_ + col];
            w[j] = (short)f2bf_bits(v);
        }
        wfrag[ks] = w;
    }

    // x staging mapping: 16 row-groups of 32 lanes, 512B-contiguous chunks
    const int srow = tid >> 5;          // 0..15
    const int scol = (tid & 31) * 4;    // 0,4,..,124
    const float* xbase = x + (size_t)(bt * 64) * (T_ * D_);

    // A-frag row (h and x): m = ms*16 + l15
    const int mrow = ms * 16 + l15;
    const int gb_a = bt * 64 + mrow;

    // gate-phase mapping
    const int bl = tid >> 3, ug = tid & 7;
    const int gb_g = bt * 64 + bl;

    unsigned int* myflag = flags + bt * 64 + lane;

    // ---- prologue: stage x_0, x-part acc for t=0, prefetch x_1 (packed) ----
    short4v rxp[8];
#pragma unroll
    for (int r = 0; r < 4; ++r) {
        const float* xp = xbase + (size_t)(r * 16 + srow) * (T_ * D_);
        int row = r * 16 + srow;
        *(short4v*)(&xls[0][row * XROW + scol]) =
            pack_bf4(*(const float4v*)(xp + scol));
        *(short4v*)(&xls[0][row * XROW + scol + 128]) =
            pack_bf4(*(const float4v*)(xp + scol + 128));
    }
    __syncthreads();
    float4v accx = {0.f, 0.f, 0.f, 0.f};
#pragma unroll
    for (int ks = 0; ks < KX; ++ks) {
        short8 a = *(const short8*)(&xls[0][mrow * XROW + ks * 32 + l4 * 8]);
        accx = __builtin_amdgcn_mfma_f32_16x16x32_bf16(a, wfrag[ks], accx, 0, 0, 0);
    }
#pragma unroll
    for (int r = 0; r < 4; ++r) {
        const float* xp = xbase + (size_t)(r * 16 + srow) * (T_ * D_) + D_;
        rxp[r * 2]     = pack_bf4(*(const float4v*)(xp + scol));
        rxp[r * 2 + 1] = pack_bf4(*(const float4v*)(xp + scol + 128));
    }

    int cur = 0;
    for (int t = 0; t < T_; ++t) {
        // ---- (A) commit prefetched x_{t+1} into the other LDS buffer ----
        // (last read of this buffer was 2 steps ago, separated by 2 barriers)
        if (t + 1 < T_) {
            unsigned short* xb = xls[(t + 1) & 1];
#pragma unroll
            for (int r = 0; r < 4; ++r) {
                int row = r * 16 + srow;
                *(short4v*)(xb + row * XROW + scol)       = rxp[r * 2];
                *(short4v*)(xb + row * XROW + scol + 128) = rxp[r * 2 + 1];
            }
        }

        // ---- (B0) acquire fence: buffer_inv drops stale L2 lines so the
        //      normal h loads below are coherent. Placed BEFORE the poll
        //      (safe by plane alternation + skew<=1); implicit waitcnt
        //      drain overlaps producer skew. Also covers t=0 memset. ----
        __builtin_amdgcn_fence(__ATOMIC_ACQUIRE, "agent");

        // ---- (B) per-wave poll: all 64 producers of this bt at step >= t ----
        if (t) {
            const unsigned tgt = (unsigned)t;
            while (true) {
                unsigned f = __hip_atomic_load(myflag, __ATOMIC_RELAXED,
                                               __HIP_MEMORY_SCOPE_AGENT);
                if (__all((int)(f >= tgt))) break;
            }
        }

        // ---- (C) h_t loads: 16 x dwordx4, NORMAL cacheable (L2 path) ----
        HAu ha[KH];
        {
            const unsigned short* hb0 =
                hbuf + ((size_t)(cur * 64 + l4) * 128 + gb_a) * 8;
#pragma unroll
            for (int ks = 0; ks < KH; ++ks) {
                const unsigned short* ap = hb0 + (size_t)ks * (4 * 128 * 8);
                asm volatile("global_load_dwordx4 %0, %1, off"
                             : "=v"(ha[ks].i4) : "v"(ap));
            }
        }

        // ---- (D) h-part MFMAs, 2 phases, dual accumulators ----
        float4v a0 = accx;                    // carries the x-part
        float4v a1 = {0.f, 0.f, 0.f, 0.f};
        asm volatile("s_waitcnt vmcnt(8)" ::: "memory");   // 8 oldest done
        __builtin_amdgcn_sched_barrier(0);
#pragma unroll
        for (int ks = 0; ks < 8; ++ks)
            a0 = __builtin_amdgcn_mfma_f32_16x16x32_bf16(
                     ha[ks].s8, wfrag[KX + ks], a0, 0, 0, 0);
        asm volatile("s_waitcnt vmcnt(0)" ::: "memory");
        __builtin_amdgcn_sched_barrier(0);
#pragma unroll
        for (int ks = 8; ks < KH; ++ks)
            a1 = __builtin_amdgcn_mfma_f32_16x16x32_bf16(
                     ha[ks].s8, wfrag[KX + ks], a1, 0, 0, 0);
        // D layout: D[row=(lane>>4)*4+r][col=lane&15]
#pragma unroll
        for (int r = 0; r < 4; ++r) {
            int row = ms * 16 + l4 * 4 + r;
            zls[row * 33 + nt * 16 + l15] = a0[r] + a1[r];
        }
        __syncthreads();

        // ---- (F) gates + direct coherent h store (coalesced shorts) ----
        {
            float zi = zls[bl * 33 + ug]      + bls[ug];
            float zf = zls[bl * 33 + 8 + ug]  + bls[8 + ug];
            float zg = zls[bl * 33 + 16 + ug] + bls[16 + ug];
            float zo = zls[bl * 33 + 24 + ug] + bls[24 + ug];
            float ig = sigmoid_fast(zi);
            float fg = sigmoid_fast(zf);
            float gg = tanh_fast(zg);
            float og = sigmoid_fast(zo);
            float cold = cls[bl * 8 + ug];
            float cnew = fg * cold + ig * gg;
            float hnew = og * tanh_fast(cnew);
            cls[bl * 8 + ug] = cnew;
            unsigned hv = (unsigned)f2bf_bits(hnew);
            unsigned short* hp = hbuf
                + ((size_t)(((t + 1) & 1) * 64 + ct) * 128 + gb_g) * 8 + ug;
            asm volatile("global_store_short %0, %1, off sc0 sc1"
                         :: "v"(hp), "v"(hv) : "memory");
            out[(size_t)gb_g * (T_ * H_) + (size_t)t * H_ + jh0 + ug] = hnew;
            if (t == T_ - 1) {
                const size_t BTH = (size_t)B_ * T_ * H_;
                out[BTH + (size_t)gb_g * H_ + jh0 + ug] = hnew;
                out[BTH + (size_t)B_ * H_ + (size_t)gb_g * H_ + jh0 + ug] = cnew;
            }
        }
        asm volatile("s_waitcnt vmcnt(0)" ::: "memory");   // h-slice ACKed
        __syncthreads();                                   // all waves stored

        // ---- (G) publish: one relaxed agent store, no RMW chain ----
        if (tid == 0)
            __hip_atomic_store(flags + bt * 64 + ct, (unsigned)(t + 1),
                               __ATOMIC_RELAXED, __HIP_MEMORY_SCOPE_AGENT);

        // ---- (H) off-path window: x-part MFMAs for t+1, prefetch x_{t+2} ----
        float4v nacc = {0.f, 0.f, 0.f, 0.f};
        if (t + 1 < T_) {
            const unsigned short* xb = xls[(t + 1) & 1];
#pragma unroll
            for (int ks = 0; ks < KX; ++ks) {
                short8 a = *(const short8*)(xb + mrow * XROW + ks * 32 + l4 * 8);
                nacc = __builtin_amdgcn_mfma_f32_16x16x32_bf16(
                           a, wfrag[ks], nacc, 0, 0, 0);
            }
            if (t + 2 < T_) {
#pragma unroll
                for (int r = 0; r < 4; ++r) {
                    const float* xp = xbase + (size_t)(r * 16 + srow) * (T_ * D_)
                                    + (size_t)(t + 2) * D_;
                    rxp[r * 2]     = pack_bf4(*(const float4v*)(xp + scol));
                    rxp[r * 2 + 1] = pack_bf4(*(const float4v*)(xp + scol + 128));
                }
            }
        }
        accx = nacc;
        cur ^= 1;
    }
}

extern "C" void kernel_launch(void* const* d_in, const int* in_sizes, int n_in,
                              void* d_out, int out_size, void* d_ws, size_t ws_size,
                              hipStream_t stream) {
    const float* x    = (const float*)d_in[0];
    const float* Wx   = (const float*)d_in[1];
    const float* Wh   = (const float*)d_in[2];
    const float* bias = (const float*)d_in[3];
    float* out = (float*)d_out;

    unsigned short* hbuf = (unsigned short*)d_ws;  // 2x[64][128][8] bf16
    const size_t hbuf_bytes = (size_t)2 * 64 * 128 * 8 * sizeof(unsigned short);
    unsigned int* flags = (unsigned int*)((char*)d_ws + hbuf_bytes);  // 128 u32

    hipMemsetAsync(d_ws, 0, hbuf_bytes + 1024, stream);

    lstm_persistent<<<dim3(NBLK), dim3(512), 0, stream>>>(
        x, Wx, Wh, bias, out, hbuf, flags);
}